// Round 13
// baseline (139.565 us; speedup 1.0000x reference)
//
#include <hip/hip_runtime.h>

typedef unsigned short u16;
typedef unsigned int u32;
typedef __attribute__((ext_vector_type(8))) short bf16x8;
typedef __attribute__((ext_vector_type(8))) unsigned short u16x8;
typedef __attribute__((ext_vector_type(4))) float f32x4;
typedef __attribute__((ext_vector_type(16))) float f32x16;

#define L_SEQ 2048
#define DMODEL 1024
#define NHEAD 16
#define EHEAD 64
#define FPROJ 7168
#define FCAT 5120
#define NEGINF -1e30f
#define LOG2E 1.44269504088896f
#define EXP2F(x) __builtin_amdgcn_exp2f(x)

__device__ __forceinline__ u16 f2bf(float f) {
  union { float f; u32 u; } v; v.f = f;
  u32 r = v.u + 0x7FFFu + ((v.u >> 16) & 1u);
  return (u16)(r >> 16);
}
__device__ __forceinline__ float bf2f(u16 h) {
  union { u32 u; float f; } v; v.u = ((u32)h) << 16;
  return v.f;
}
__device__ __forceinline__ float gelu_f(float x) {
  float y = 0.7978845608028654f * (x + 0.044715f * x * x * x);
  float t = __expf(-2.0f * fabsf(y));
  float th = (1.0f - t) / (1.0f + t);
  th = (y < 0.0f) ? -th : th;
  return 0.5f * x * (1.0f + th);
}
__device__ __forceinline__ void gld16(void* lds, const void* g) {
  __builtin_amdgcn_global_load_lds((const __attribute__((address_space(1))) u32*)g,
                                   (__attribute__((address_space(3))) u32*)lds, 16, 0, 0);
}

// -------- f32->bf16 weight convert (x2) + theta->(cos,sin) f32 table, one dispatch --------
__global__ __launch_bounds__(256) void cvt3_kernel(const float* __restrict__ a,
                                                   u16* __restrict__ oa, int na4,
                                                   const float* __restrict__ b,
                                                   u16* __restrict__ ob, int nb4,
                                                   const float* __restrict__ theta,
                                                   float2* __restrict__ tab, int nt4) {
  int i = blockIdx.x * 256 + threadIdx.x;
  if (i < na4 + nb4) {
    const float* src;
    u16* dst;
    int j;
    if (i < na4) { src = a; dst = oa; j = i; }
    else         { src = b; dst = ob; j = i - na4; }
    float4 v = ((const float4*)src)[j];
    ((u32*)dst)[2 * j] = (u32)f2bf(v.x) | ((u32)f2bf(v.y) << 16);
    ((u32*)dst)[2 * j + 1] = (u32)f2bf(v.z) | ((u32)f2bf(v.w) << 16);
    return;
  }
  int j = i - na4 - nb4;
  if (j >= nt4) return;
  float4 t = ((const float4*)theta)[j];
  float2 o0, o1, o2, o3;
  __sincosf(t.x, &o0.y, &o0.x);
  __sincosf(t.y, &o1.y, &o1.x);
  __sincosf(t.z, &o2.y, &o2.x);
  __sincosf(t.w, &o3.y, &o3.x);
  tab[4 * j + 0] = o0;
  tab[4 * j + 1] = o1;
  tab[4 * j + 2] = o2;
  tab[4 * j + 3] = o3;
}

// ---------------- RMSNorm * (1+scale) -> bf16 ----------------
__global__ __launch_bounds__(256) void rmsnorm_kernel(const float* __restrict__ x,
                                                      const float* __restrict__ scale,
                                                      u16* __restrict__ xn) {
  int row = blockIdx.x;
  const float4 v = ((const float4*)(x + (size_t)row * DMODEL))[threadIdx.x];
  float ss = v.x * v.x + v.y * v.y + v.z * v.z + v.w * v.w;
#pragma unroll
  for (int m = 1; m < 64; m <<= 1) ss += __shfl_xor(ss, m);
  __shared__ float ws[4];
  if ((threadIdx.x & 63) == 0) ws[threadIdx.x >> 6] = ss;
  __syncthreads();
  float tot = ws[0] + ws[1] + ws[2] + ws[3];
  float r = rsqrtf(tot * (1.0f / DMODEL) + 1e-6f);
  float4 sc = ((const float4*)scale)[threadIdx.x];
  u32 w0 = (u32)f2bf(v.x * r * (1.0f + sc.x)) | ((u32)f2bf(v.y * r * (1.0f + sc.y)) << 16);
  u32 w1 = (u32)f2bf(v.z * r * (1.0f + sc.z)) | ((u32)f2bf(v.w * r * (1.0f + sc.w)) << 16);
  u32* dst = (u32*)(xn + (size_t)row * DMODEL);
  dst[2 * threadIdx.x] = w0;
  dst[2 * threadIdx.x + 1] = w1;
}

// ---------------- 256x256 8-phase GEMM (R8 schedule) ----------------
// OUTMODE 1 (GEMM1): fused epilogue — bn 0..3 -> q (norm+RoPE->qb), 4..7 -> k (->kb),
//   8..11 -> v (head-transpose ->vb), 12..27 -> gelu -> hb.  proj eliminated.
// OUTMODE 2 (GEMM2): bf16 split-K partial at C0 + blockIdx.y*M*N.
__device__ __forceinline__ void stage_half(u16* lds, const u16* g, int K, int tid) {
#pragma unroll
  for (int i = 0; i < 2; ++i) {
    int idx = tid + i * 512;
    int r = idx >> 3;
    int gcb = ((idx & 7) << 4) ^ ((r & 7) << 4);
    gld16((char*)lds + idx * 16, (const char*)g + (size_t)r * K * 2 + gcb);
  }
}

#define GFENCE asm volatile("" ::: "memory")
#define VMW0 asm volatile("s_waitcnt vmcnt(0)" ::: "memory")
#define VMW2 asm volatile("s_waitcnt vmcnt(2)" ::: "memory")
#define ST_A(BUF, T, HALF) stage_half(sA + (BUF) * 16384 + (HALF) * 8192, \
    Ab + (size_t)((HALF) * 128) * K + (T) * 64, K, tid)
#define ST_B(BUF, T, HALF) stage_half(sB + (BUF) * 16384 + (HALF) * 8192, \
    Bb + (size_t)((HALF) * 128) * K + (T) * 64, K, tid)

#define PHASE(HM, KH, BUFB, DOVM, STCODE) do { \
    const char* ab_ = (const char*)sA + (BUFB) * 32768 + (HM) * 16384 + frow * 128 + ((KH) ? co1 : co0); \
    const char* bb_ = (const char*)sB + (BUFB) * 32768 + (wn * 32 + frow) * 128 + ((KH) ? co1 : co0); \
    bf16x8 af_[8], bv_[2]; \
    _Pragma("unroll") \
    for (int mr = 0; mr < 8; ++mr) af_[mr] = *(const bf16x8*)(ab_ + mr * 2048); \
    bv_[0] = *(const bf16x8*)(bb_); \
    bv_[1] = *(const bf16x8*)(bb_ + 2048); \
    GFENCE; \
    STCODE; \
    if (DOVM) VMW2; \
    __builtin_amdgcn_s_barrier(); \
    __builtin_amdgcn_s_setprio(1); \
    _Pragma("unroll") \
    for (int mr = 0; mr < 8; ++mr) { \
      acc[(HM) * 8 + mr][0] = __builtin_amdgcn_mfma_f32_16x16x32_bf16(af_[mr], bv_[0], acc[(HM) * 8 + mr][0], 0, 0, 0); \
      acc[(HM) * 8 + mr][1] = __builtin_amdgcn_mfma_f32_16x16x32_bf16(af_[mr], bv_[1], acc[(HM) * 8 + mr][1], 0, 0, 0); \
    } \
    __builtin_amdgcn_s_setprio(0); \
    __builtin_amdgcn_s_barrier(); \
  } while (0)

template <int OUTMODE>
__global__ __launch_bounds__(512, 2) void gemm256(const u16* __restrict__ A,
                                                  const u16* __restrict__ B,
                                                  u16* __restrict__ C0,
                                                  u16* __restrict__ C1,
                                                  u16* __restrict__ qb,
                                                  u16* __restrict__ kb,
                                                  u16* __restrict__ vb,
                                                  const float2* __restrict__ tab,
                                                  const float* __restrict__ ascale,
                                                  int M, int N, int K) {
  __shared__ __align__(16) u16 smem[65536];
  u16* const sA = smem;
  u16* const sB = smem + 32768;
  const int tid = threadIdx.x;
  const int lane = tid & 63;
  const int wn = tid >> 6;
  const int frow = lane & 15;
  const int kbyte = ((lane >> 4) & 3) << 4;
  const int sw = (frow & 7) << 4;
  const int co0 = kbyte ^ sw;
  const int co1 = (64 | kbyte) ^ sw;

  const int nbx = N >> 8;
  const int nbm = (int)gridDim.x / nbx;
  const int v = (blockIdx.x & 7) * ((int)gridDim.x >> 3) + ((int)blockIdx.x >> 3);
  const int bm = v % nbm, bn = v / nbm;
  const int kper = K / (int)gridDim.y;
  const int kbeg = blockIdx.y * kper;
  const u16* Ab = A + (size_t)(bm * 256) * K + kbeg;
  const u16* Bb = B + (size_t)(bn * 256) * K + kbeg;

  f32x4 acc[16][2] = {};

  const int NT = kper >> 6;
  ST_A(0, 0, 0); ST_B(0, 0, 0); ST_B(0, 0, 1); ST_A(0, 0, 1); ST_A(1, 1, 0);
  VMW2;
  __builtin_amdgcn_s_barrier();

  for (int kt = 0; kt < NT; kt += 2) {
    const int t1 = kt + 1;
    const int t2 = (kt + 2 >= NT) ? kt + 2 - NT : kt + 2;
    const int t3 = (kt + 3 >= NT) ? kt + 3 - NT : kt + 3;
    PHASE(0, 0, 0, 0, ST_B(1, t1, 0));
    PHASE(0, 1, 0, 0, ST_B(1, t1, 1));
    PHASE(1, 0, 0, 0, ST_A(1, t1, 1));
    PHASE(1, 1, 0, 1, ST_A(0, t2, 0));
    PHASE(0, 0, 1, 0, ST_B(0, t2, 0));
    PHASE(0, 1, 1, 0, ST_B(0, t2, 1));
    PHASE(1, 0, 1, 0, ST_A(0, t2, 1));
    PHASE(1, 1, 1, 1, ST_A(1, t3, 0));
  }

  VMW0;
  __syncthreads();

  const bool up = (OUTMODE == 1) && (bn >= 12);
  u16* const Cp2 = (OUTMODE == 2) ? C0 + (size_t)blockIdx.y * M * N : nullptr;

#pragma unroll
  for (int hm = 0; hm < 2; ++hm) {
    // acc -> LDS [128][272]
#pragma unroll
    for (int m8 = 0; m8 < 8; ++m8) {
#pragma unroll
      for (int nr = 0; nr < 2; ++nr) {
        int col = wn * 32 + nr * 16 + frow;
#pragma unroll
        for (int r = 0; r < 4; ++r) {
          float vv = acc[hm * 8 + m8][nr][r];
          smem[(m8 * 16 + ((lane >> 4) * 4) + r) * 272 + col] = f2bf(up ? gelu_f(vv) : vv);
        }
      }
    }
    __syncthreads();

    if (OUTMODE == 2) {
#pragma unroll
      for (int j = 0; j < 8; ++j) {
        int row = j * 16 + (tid >> 5);
        int c16 = (tid & 31) * 8;
        u16x8 vv = *(const u16x8*)&smem[row * 272 + c16];
        *(u16x8*)(Cp2 + (size_t)(bm * 256 + hm * 128 + row) * N + bn * 256 + c16) = vv;
      }
    } else if (up) {
#pragma unroll
      for (int j = 0; j < 8; ++j) {
        int row = j * 16 + (tid >> 5);
        int c16 = (tid & 31) * 8;
        u16x8 vv = *(const u16x8*)&smem[row * 272 + c16];
        *(u16x8*)(C1 + (size_t)(bm * 256 + hm * 128 + row) * FCAT + (bn * 256 + c16 - 2048)) = vv;
      }
    } else if (bn >= 8) {
      // v tiles: head-transpose copy to vb[hd][l][e]
#pragma unroll
      for (int j = 0; j < 8; ++j) {
        int row = j * 16 + (tid >> 5);
        int c16 = (tid & 31) * 8;
        int gcv = bn * 256 + c16 - 2048;
        int hd = gcv >> 6, e0 = gcv & 63;
        int l = bm * 256 + hm * 128 + row;
        u16x8 vv = *(const u16x8*)&smem[row * 272 + c16];
        *(u16x8*)(vb + ((size_t)hd * L_SEQ + l) * 64 + e0) = vv;
      }
    } else {
      // q/k tiles: per-thread (row, head) norm + RoPE via precomputed table
      int r = tid >> 2, ch = tid & 3;
      int l = bm * 256 + hm * 128 + r;
      int gc0 = bn * 256 + ch * 64;
      int hd = (gc0 & 1023) >> 6;
      const bool isq = (bn < 4);
      const u16* lr = &smem[r * 272 + ch * 64];
      float ss = 0.f;
#pragma unroll
      for (int j8 = 0; j8 < 8; ++j8) {
        u16x8 vv = *(const u16x8*)(lr + j8 * 8);
#pragma unroll
        for (int e = 0; e < 8; ++e) { float f = bf2f(vv[e]); ss += f * f; }
      }
      float s = sqrtf(ascale[hd]) * rsqrtf(ss + 1e-6f);
      if (isq) s *= LOG2E;
      const float2* tp = tab + ((size_t)hd * L_SEQ + l) * 32;
      u16 ob[64];
#pragma unroll
      for (int e = 0; e < 32; ++e) {
        float2 cz = tp[e];
        float x0 = bf2f(lr[e]) * s;
        float x1 = bf2f(lr[e + 32]) * s;
        ob[e] = f2bf(x0 * cz.x - x1 * cz.y);
        ob[e + 32] = f2bf(x1 * cz.x + x0 * cz.y);
      }
      u16* dst = (isq ? qb : kb) + ((size_t)hd * L_SEQ + l) * 64;
#pragma unroll
      for (int j8 = 0; j8 < 8; ++j8) *(u16x8*)(dst + j8 * 8) = *(const u16x8*)(ob + j8 * 8);
    }
    __syncthreads();
  }
}

// ---------------- combine 8 bf16 split-K partials + skip -> f32 out ----------------
__global__ __launch_bounds__(256) void combine8(const u16* __restrict__ part,
                                                const float* __restrict__ x,
                                                float* __restrict__ out) {
  size_t i = (size_t)(blockIdx.x * 256 + threadIdx.x) * 8;
  float4 x0 = *(const float4*)(x + i);
  float4 x1 = *(const float4*)(x + i + 4);
  float s[8] = {x0.x, x0.y, x0.z, x0.w, x1.x, x1.y, x1.z, x1.w};
#pragma unroll
  for (int p = 0; p < 8; ++p) {
    u16x8 v = *(const u16x8*)(part + (size_t)p * (L_SEQ * DMODEL) + i);
#pragma unroll
    for (int j = 0; j < 8; ++j) s[j] += bf2f(v[j]);
  }
  float4 o0 = {s[0], s[1], s[2], s[3]};
  float4 o1 = {s[4], s[5], s[6], s[7]};
  *(float4*)(out + i) = o0;
  *(float4*)(out + i + 4) = o1;
}

// ---------------- causal flash attention, split-KV x4, 32x32 MFMA ----------------
__global__ __launch_bounds__(128, 4) void attn_kernel(const u16* __restrict__ qb,
                                                      const u16* __restrict__ kb,
                                                      const u16* __restrict__ vb,
                                                      u16* __restrict__ po,
                                                      float* __restrict__ pm,
                                                      float* __restrict__ pl) {
  const int bid = blockIdx.x;
  const int s = 31 - (bid >> 6);
  const int hd = (bid >> 2) & 15;
  const int c = bid & 3;
  const int tid = threadIdx.x;
  const int lane = tid & 63;
  const int w = tid >> 6;
  const int h = lane >> 5;
  const int ql = lane & 31;
  const int qg = s * 64 + w * 32 + ql;
  const int nt = s + 1;
  const int t0 = (c * nt) >> 2;
  const int t1 = ((c + 1) * nt) >> 2;

  __shared__ u16 sK[64 * 64];
  __shared__ u16 sVT[64 * 64];

  const u16* Kh = kb + (size_t)hd * L_SEQ * EHEAD;
  const u16* Vh = vb + (size_t)hd * L_SEQ * EHEAD;
  const u16* Qh = qb + (size_t)hd * L_SEQ * EHEAD;

  bf16x8 qf[4];
#pragma unroll
  for (int es = 0; es < 4; ++es)
    qf[es] = *(const bf16x8*)(Qh + (size_t)qg * EHEAD + es * 16 + h * 8);

  f32x16 oa[2] = {};
  float m = NEGINF, lsum = 0.0f;

  const int vk = (tid & 15) * 4;
  const int ve = (tid >> 4) * 8;

  for (int kt = t0; kt < t1; ++kt) {
    const int k0 = kt * 64;
    __syncthreads();
#pragma unroll
    for (int i = 0; i < 4; ++i) {
      int r = w * 32 + i * 8 + (lane >> 3);
      const u16* src = Kh + (size_t)(k0 + r) * EHEAD + (((lane & 7) ^ (r & 7)) << 3);
      gld16(sK + (w * 32 + i * 8) * 64 + lane * 8, src);
    }
    u16x8 vr[4];
#pragma unroll
    for (int j = 0; j < 4; ++j)
      vr[j] = *(const u16x8*)(Vh + (size_t)(k0 + vk + j) * EHEAD + ve);
#pragma unroll
    for (int e = 0; e < 8; ++e) {
      int row = ve + e;
      int boff = row * 128 + ((((vk >> 3) ^ (row & 7)) << 4) | ((vk & 4) << 1));
      ushort4 pv;
      pv.x = vr[0][e]; pv.y = vr[1][e]; pv.z = vr[2][e]; pv.w = vr[3][e];
      *(ushort4*)((char*)sVT + boff) = pv;
    }
    __syncthreads();

    f32x16 st[2];
#pragma unroll
    for (int t = 0; t < 2; ++t) {
      f32x16 a = {};
      __builtin_amdgcn_s_setprio(1);
#pragma unroll
      for (int es = 0; es < 4; ++es) {
        int row = t * 32 + ql;
        int boff = row * 128 + (((es * 2 + h) ^ (row & 7)) << 4);
        bf16x8 kf = *(const bf16x8*)((const char*)sK + boff);
        a = __builtin_amdgcn_mfma_f32_32x32x16_bf16(kf, qf[es], a, 0, 0, 0);
      }
      __builtin_amdgcn_s_setprio(0);
      st[t] = a;
    }

    float p[2][16];
    float mx = NEGINF;
    const bool edge = (kt == s);
#pragma unroll
    for (int t = 0; t < 2; ++t)
#pragma unroll
      for (int r = 0; r < 16; ++r) {
        float v = st[t][r];
        if (edge) {
          int kg = k0 + t * 32 + (r & 3) + ((r >> 2) << 3) + h * 4;
          v = (kg > qg) ? NEGINF : v;
        }
        p[t][r] = v;
        mx = fmaxf(mx, v);
      }
    mx = fmaxf(mx, __shfl_xor(mx, 32));
    if (!__all(mx - m <= 8.0f)) {
      float mnew = fmaxf(m, mx);
      float alpha = EXP2F(m - mnew);
      lsum *= alpha;
#pragma unroll
      for (int et = 0; et < 2; ++et)
#pragma unroll
        for (int r = 0; r < 16; ++r) oa[et][r] *= alpha;
      m = mnew;
    }
    float ps = 0.0f;
#pragma unroll
    for (int t = 0; t < 2; ++t)
#pragma unroll
      for (int r = 0; r < 16; ++r) {
        float e_ = EXP2F(p[t][r] - m);
        p[t][r] = e_;
        ps += e_;
      }
    ps += __shfl_xor(ps, 32);
    lsum += ps;

    u32 pk_[2][8];
#pragma unroll
    for (int t = 0; t < 2; ++t)
#pragma unroll
      for (int i = 0; i < 8; ++i)
        asm("v_cvt_pk_bf16_f32 %0, %1, %2" : "=v"(pk_[t][i]) : "v"(p[t][2 * i]), "v"(p[t][2 * i + 1]));

#pragma unroll
    for (int ks = 0; ks < 4; ++ks) {
      const int tp = ks >> 1, base = (ks & 1) * 4;
      u32 s0 = h ? pk_[tp][base + 0] : pk_[tp][base + 2];
      u32 s1 = h ? pk_[tp][base + 1] : pk_[tp][base + 3];
      u32 r0 = (u32)__shfl_xor((int)s0, 32);
      u32 r1 = (u32)__shfl_xor((int)s1, 32);
      union { u32 u[4]; bf16x8 v; } pf;
      pf.u[0] = h ? r0 : pk_[tp][base + 0];
      pf.u[1] = h ? r1 : pk_[tp][base + 1];
      pf.u[2] = h ? pk_[tp][base + 2] : r0;
      pf.u[3] = h ? pk_[tp][base + 3] : r1;
      __builtin_amdgcn_s_setprio(1);
#pragma unroll
      for (int et = 0; et < 2; ++et) {
        int row = et * 32 + ql;
        int boff = row * 128 + (((ks * 2 + h) ^ (row & 7)) << 4);
        bf16x8 vf = *(const bf16x8*)((const char*)sVT + boff);
        oa[et] = __builtin_amdgcn_mfma_f32_32x32x16_bf16(vf, pf.v, oa[et], 0, 0, 0);
      }
      __builtin_amdgcn_s_setprio(0);
    }
  }

  const size_t pidx = (size_t)(s * 16 + hd) * 4 + c;
  u16* orow = po + pidx * 4096 + (size_t)(w * 32 + ql) * 64;
#pragma unroll
  for (int et = 0; et < 2; ++et)
#pragma unroll
    for (int g = 0; g < 4; ++g) {
      ushort4 ov;
      ov.x = f2bf(oa[et][4 * g + 0]);
      ov.y = f2bf(oa[et][4 * g + 1]);
      ov.z = f2bf(oa[et][4 * g + 2]);
      ov.w = f2bf(oa[et][4 * g + 3]);
      *(ushort4*)(orow + et * 32 + g * 8 + h * 4) = ov;
    }
  if (h == 0) {
    pm[pidx * 64 + w * 32 + ql] = m;
    pl[pidx * 64 + w * 32 + ql] = lsum;
  }
}

// ---------------- merge split-KV partials -> hb ----------------
__global__ __launch_bounds__(256) void attn_merge(const u16* __restrict__ po,
                                                  const float* __restrict__ pm,
                                                  const float* __restrict__ pl,
                                                  u16* __restrict__ hb) {
  const int sh = blockIdx.x;
  const int s = sh >> 4, hd = sh & 15;
  const int r = threadIdx.x >> 2;
  const int ec = (threadIdx.x & 3) << 4;
  float mc[4], wgt[4];
  float M = NEGINF;
#pragma unroll
  for (int c = 0; c < 4; ++c) {
    mc[c] = pm[(size_t)(sh * 4 + c) * 64 + r];
    M = fmaxf(M, mc[c]);
  }
  float L = 0.0f;
#pragma unroll
  for (int c = 0; c < 4; ++c) {
    wgt[c] = EXP2F(mc[c] - M);
    L += pl[(size_t)(sh * 4 + c) * 64 + r] * wgt[c];
  }
  float inv = 1.0f / L;
  float o[16] = {};
#pragma unroll
  for (int c = 0; c < 4; ++c) {
    const u16* pp = po + (size_t)(sh * 4 + c) * 4096 + r * 64 + ec;
    u16x8 v0 = *(const u16x8*)pp;
    u16x8 v1 = *(const u16x8*)(pp + 8);
#pragma unroll
    for (int j = 0; j < 8; ++j) {
      o[j] += wgt[c] * bf2f(v0[j]);
      o[8 + j] += wgt[c] * bf2f(v1[j]);
    }
  }
  u16* dst = hb + (size_t)(s * 64 + r) * FCAT + hd * EHEAD + ec;
  u16x8 out0, out1;
#pragma unroll
  for (int j = 0; j < 8; ++j) {
    out0[j] = f2bf(o[j] * inv);
    out1[j] = f2bf(o[8 + j] * inv);
  }
  *(u16x8*)dst = out0;
  *(u16x8*)(dst + 8) = out1;
}

extern "C" void kernel_launch(void* const* d_in, const int* in_sizes, int n_in,
                              void* d_out, int out_size, void* d_ws, size_t ws_size,
                              hipStream_t stream) {
  const float* x = (const float*)d_in[0];
  const float* theta = (const float*)d_in[1];
  const float* scale = (const float*)d_in[2];
  const float* w_in = (const float*)d_in[3];
  const float* w_out = (const float*)d_in[4];
  const float* attn_scale = (const float*)d_in[5];
  float* out = (float*)d_out;

  char* ws = (char*)d_ws;
  u16* w_out_b = (u16*)ws;   ws += (size_t)DMODEL * FCAT * 2;          // live: GEMM2 B
  u16* hb = (u16*)ws;        ws += (size_t)L_SEQ * FCAT * 2;           // live: GEMM2 A
  u16* xn = (u16*)ws;        ws += (size_t)L_SEQ * DMODEL * 2;         // dead after GEMM1
  u16* w_in_b = (u16*)ws;    ws += (size_t)FPROJ * DMODEL * 2;         // dead after GEMM1
  u16* qb = (u16*)ws;        ws += (size_t)NHEAD * L_SEQ * EHEAD * 2;  // dead after attn
  u16* kb = (u16*)ws;        ws += (size_t)NHEAD * L_SEQ * EHEAD * 2;
  u16* vb = (u16*)ws;        ws += (size_t)NHEAD * L_SEQ * EHEAD * 2;
  float2* tab = (float2*)ws; ws += (size_t)NHEAD * L_SEQ * 32 * sizeof(float2);  // dead after GEMM1
  // attn partials overlay dead xn+w_in_b (18.9MB): po 16.8 + pm/pl 1.0
  u16* po = xn;
  float* pm = (float*)(po + (size_t)512 * 4 * 4096);
  float* pl = pm + 512 * 4 * 64;
  // GEMM2 split-K partials (33.5MB) overlay xn..tab (39.4MB) — all dead by GEMM2
  u16* part = xn;

  const int na4 = FPROJ * DMODEL / 4, nb4 = DMODEL * FCAT / 4;
  const int nt4 = NHEAD * L_SEQ * 32 / 4;
  cvt3_kernel<<<(na4 + nb4 + nt4 + 255) / 256, 256, 0, stream>>>(
      w_in, w_in_b, na4, w_out, w_out_b, nb4, theta, tab, nt4);
  rmsnorm_kernel<<<L_SEQ, 256, 0, stream>>>(x, scale, xn);
  gemm256<1><<<(L_SEQ / 256) * (FPROJ / 256), 512, 0, stream>>>(
      xn, w_in_b, nullptr, hb, qb, kb, vb, tab, attn_scale, L_SEQ, FPROJ, DMODEL);
  attn_kernel<<<2048, 128, 0, stream>>>(qb, kb, vb, po, pm, pl);
  attn_merge<<<512, 256, 0, stream>>>(po, pm, pl, hb);
  gemm256<2><<<dim3((L_SEQ / 256) * (DMODEL / 256), 8), 512, 0, stream>>>(
      hb, w_out_b, part, nullptr, nullptr, nullptr, nullptr, nullptr, nullptr,
      L_SEQ, DMODEL, FCAT);
  combine8<<<L_SEQ * DMODEL / 8 / 256, 256, 0, stream>>>(part, x, out);
}

// Round 14
// 133.574 us; speedup vs baseline: 1.0448x; 1.0448x over previous
//
#include <hip/hip_runtime.h>

typedef unsigned short u16;
typedef unsigned int u32;
typedef __attribute__((ext_vector_type(8))) short bf16x8;
typedef __attribute__((ext_vector_type(8))) unsigned short u16x8;
typedef __attribute__((ext_vector_type(4))) float f32x4;
typedef __attribute__((ext_vector_type(16))) float f32x16;

#define L_SEQ 2048
#define DMODEL 1024
#define NHEAD 16
#define EHEAD 64
#define FPROJ 7168
#define FCAT 5120
#define NEGINF -1e30f
#define LOG2E 1.44269504088896f
#define EXP2F(x) __builtin_amdgcn_exp2f(x)

__device__ __forceinline__ u16 f2bf(float f) {
  union { float f; u32 u; } v; v.f = f;
  u32 r = v.u + 0x7FFFu + ((v.u >> 16) & 1u);
  return (u16)(r >> 16);
}
__device__ __forceinline__ float bf2f(u16 h) {
  union { u32 u; float f; } v; v.u = ((u32)h) << 16;
  return v.f;
}
__device__ __forceinline__ float gelu_f(float x) {
  float y = 0.7978845608028654f * (x + 0.044715f * x * x * x);
  float t = __expf(-2.0f * fabsf(y));
  float th = (1.0f - t) / (1.0f + t);
  th = (y < 0.0f) ? -th : th;
  return 0.5f * x * (1.0f + th);
}
__device__ __forceinline__ void gld16(void* lds, const void* g) {
  __builtin_amdgcn_global_load_lds((const __attribute__((address_space(1))) u32*)g,
                                   (__attribute__((address_space(3))) u32*)lds, 16, 0, 0);
}

// -------- prep: f32->bf16 weight convert (x2) + RMSNorm, one dispatch --------
__global__ __launch_bounds__(256) void prep_kernel(const float* __restrict__ a,
                                                   u16* __restrict__ oa, int na4,
                                                   const float* __restrict__ b,
                                                   u16* __restrict__ ob, int nb4,
                                                   int ncvt,
                                                   const float* __restrict__ x,
                                                   const float* __restrict__ scale,
                                                   u16* __restrict__ xn) {
  if ((int)blockIdx.x < ncvt) {
    int i = blockIdx.x * 256 + threadIdx.x;
    const float* src;
    u16* dst;
    int j;
    if (i < na4) { src = a; dst = oa; j = i; }
    else { j = i - na4; if (j >= nb4) return; src = b; dst = ob; }
    float4 v = ((const float4*)src)[j];
    ((u32*)dst)[2 * j] = (u32)f2bf(v.x) | ((u32)f2bf(v.y) << 16);
    ((u32*)dst)[2 * j + 1] = (u32)f2bf(v.z) | ((u32)f2bf(v.w) << 16);
    return;
  }
  int row = blockIdx.x - ncvt;
  const float4 v = ((const float4*)(x + (size_t)row * DMODEL))[threadIdx.x];
  float ss = v.x * v.x + v.y * v.y + v.z * v.z + v.w * v.w;
#pragma unroll
  for (int m = 1; m < 64; m <<= 1) ss += __shfl_xor(ss, m);
  __shared__ float ws[4];
  if ((threadIdx.x & 63) == 0) ws[threadIdx.x >> 6] = ss;
  __syncthreads();
  float tot = ws[0] + ws[1] + ws[2] + ws[3];
  float r = rsqrtf(tot * (1.0f / DMODEL) + 1e-6f);
  float4 sc = ((const float4*)scale)[threadIdx.x];
  u32 w0 = (u32)f2bf(v.x * r * (1.0f + sc.x)) | ((u32)f2bf(v.y * r * (1.0f + sc.y)) << 16);
  u32 w1 = (u32)f2bf(v.z * r * (1.0f + sc.z)) | ((u32)f2bf(v.w * r * (1.0f + sc.w)) << 16);
  u32* dst = (u32*)(xn + (size_t)row * DMODEL);
  dst[2 * threadIdx.x] = w0;
  dst[2 * threadIdx.x + 1] = w1;
}

// ---------------- 256x256 8-phase GEMM, single phase-leading barrier ----------------
// Ledger (stage -> first read): B1h0 P1->P5, B1h1 P2->P5, A1h1 P3->P7, A0h0 P4->nP1,
// B0h0 P5->nP1, B0h1 P6->nP1, A0h1 P7->nP3, A1h0 P8->nP5.
// Waits: VMW6@P2, VMW4@P4, VMW6@P6, VMW4@P8. Phase-leading s_barrier makes
// "all waves passed prior VMW" hold before each phase's ds_read (edge-checked).
// Stages never write regions read in their own phase -> skew<=1 phase is safe.
__device__ __forceinline__ void stage_half(u16* lds, const u16* g, int K, int tid) {
#pragma unroll
  for (int i = 0; i < 2; ++i) {
    int idx = tid + i * 512;
    int r = idx >> 3;
    int gcb = ((idx & 7) << 4) ^ ((r & 7) << 4);
    gld16((char*)lds + idx * 16, (const char*)g + (size_t)r * K * 2 + gcb);
  }
}

#define GFENCE asm volatile("" ::: "memory")
#define VMW0 asm volatile("s_waitcnt vmcnt(0)" ::: "memory")
#define VMW2 asm volatile("s_waitcnt vmcnt(2)" ::: "memory")
#define VMW4 asm volatile("s_waitcnt vmcnt(4)" ::: "memory")
#define VMW6 asm volatile("s_waitcnt vmcnt(6)" ::: "memory")
#define ST_A(BUF, T, HALF) stage_half(sA + (BUF) * 16384 + (HALF) * 8192, \
    Ab + (size_t)((HALF) * 128) * K + (T) * 64, K, tid)
#define ST_B(BUF, T, HALF) stage_half(sB + (BUF) * 16384 + (HALF) * 8192, \
    Bb + (size_t)((HALF) * 128) * K + (T) * 64, K, tid)

#define PHASE(HM, KH, BUFB, WCODE, STCODE) do { \
    __builtin_amdgcn_s_barrier(); \
    const char* ab_ = (const char*)sA + (BUFB) * 32768 + (HM) * 16384 + frow * 128 + ((KH) ? co1 : co0); \
    const char* bb_ = (const char*)sB + (BUFB) * 32768 + (wn * 32 + frow) * 128 + ((KH) ? co1 : co0); \
    bf16x8 af_[8], bv_[2]; \
    _Pragma("unroll") \
    for (int mr = 0; mr < 8; ++mr) af_[mr] = *(const bf16x8*)(ab_ + mr * 2048); \
    bv_[0] = *(const bf16x8*)(bb_); \
    bv_[1] = *(const bf16x8*)(bb_ + 2048); \
    GFENCE; \
    STCODE; \
    WCODE; \
    __builtin_amdgcn_s_setprio(1); \
    _Pragma("unroll") \
    for (int mr = 0; mr < 8; ++mr) { \
      acc[(HM) * 8 + mr][0] = __builtin_amdgcn_mfma_f32_16x16x32_bf16(af_[mr], bv_[0], acc[(HM) * 8 + mr][0], 0, 0, 0); \
      acc[(HM) * 8 + mr][1] = __builtin_amdgcn_mfma_f32_16x16x32_bf16(af_[mr], bv_[1], acc[(HM) * 8 + mr][1], 0, 0, 0); \
    } \
    __builtin_amdgcn_s_setprio(0); \
  } while (0)

template <int OUTMODE>
__global__ __launch_bounds__(512, 2) void gemm256(const u16* __restrict__ A,
                                                  const u16* __restrict__ B,
                                                  u16* __restrict__ C0,
                                                  u16* __restrict__ C1,
                                                  int M, int N, int K) {
  __shared__ __align__(16) u16 smem[65536];
  u16* const sA = smem;
  u16* const sB = smem + 32768;
  const int tid = threadIdx.x;
  const int lane = tid & 63;
  const int wn = tid >> 6;
  const int frow = lane & 15;
  const int kbyte = ((lane >> 4) & 3) << 4;
  const int sw = (frow & 7) << 4;
  const int co0 = kbyte ^ sw;
  const int co1 = (64 | kbyte) ^ sw;

  const int nbx = N >> 8;
  const int nbm = (int)gridDim.x / nbx;
  const int v = (blockIdx.x & 7) * ((int)gridDim.x >> 3) + ((int)blockIdx.x >> 3);
  const int bm = v % nbm, bn = v / nbm;
  const int kper = K / (int)gridDim.y;
  const int kbeg = blockIdx.y * kper;
  const u16* Ab = A + (size_t)(bm * 256) * K + kbeg;
  const u16* Bb = B + (size_t)(bn * 256) * K + kbeg;

  f32x4 acc[16][2] = {};

  const int NT = kper >> 6;
  // prologue: loads ordered A0h0,B0h0,B0h1,A0h1,A1h0; VMW2 -> first three done.
  // P1's leading barrier supplies the collective edge.
  ST_A(0, 0, 0); ST_B(0, 0, 0); ST_B(0, 0, 1); ST_A(0, 0, 1); ST_A(1, 1, 0);
  VMW2;

  for (int kt = 0; kt < NT; kt += 2) {
    const int t1 = kt + 1;
    const int t2 = (kt + 2 >= NT) ? kt + 2 - NT : kt + 2;
    const int t3 = (kt + 3 >= NT) ? kt + 3 - NT : kt + 3;
    PHASE(0, 0, 0, , ST_B(1, t1, 0));
    PHASE(0, 1, 0, VMW6, ST_B(1, t1, 1));
    PHASE(1, 0, 0, , ST_A(1, t1, 1));
    PHASE(1, 1, 0, VMW4, ST_A(0, t2, 0));
    PHASE(0, 0, 1, , ST_B(0, t2, 0));
    PHASE(0, 1, 1, VMW6, ST_B(0, t2, 1));
    PHASE(1, 0, 1, , ST_A(0, t2, 1));
    PHASE(1, 1, 1, VMW4, ST_A(1, t3, 0));
  }

  // drain outstanding tail prefetch (it writes into smem, which we now reuse)
  VMW0;
  __syncthreads();

  const bool up = (OUTMODE == 1) && (bn >= 12);
  u16* const Cp2 = (OUTMODE == 2) ? C0 + (size_t)blockIdx.y * M * N : nullptr;

#pragma unroll
  for (int hm = 0; hm < 2; ++hm) {
#pragma unroll
    for (int m8 = 0; m8 < 8; ++m8) {
#pragma unroll
      for (int nr = 0; nr < 2; ++nr) {
        int col = wn * 32 + nr * 16 + frow;
#pragma unroll
        for (int r = 0; r < 4; ++r) {
          float vv = acc[hm * 8 + m8][nr][r];
          smem[(m8 * 16 + ((lane >> 4) * 4) + r) * 272 + col] = f2bf(up ? gelu_f(vv) : vv);
        }
      }
    }
    __syncthreads();
#pragma unroll
    for (int j = 0; j < 8; ++j) {
      int row = j * 16 + (tid >> 5);
      int c16 = (tid & 31) * 8;
      u16x8 vv = *(const u16x8*)&smem[row * 272 + c16];
      int gr = bm * 256 + hm * 128 + row;
      int gc = bn * 256 + c16;
      if (OUTMODE == 1) {
        if (!up) *(u16x8*)(C0 + (size_t)gr * (3 * DMODEL) + gc) = vv;
        else     *(u16x8*)(C1 + (size_t)gr * FCAT + (gc - 2048)) = vv;
      } else {
        *(u16x8*)(Cp2 + (size_t)gr * N + gc) = vv;
      }
    }
    __syncthreads();
  }
}

// ---------------- combine 8 bf16 split-K partials + skip -> f32 out ----------------
__global__ __launch_bounds__(256) void combine8(const u16* __restrict__ part,
                                                const float* __restrict__ x,
                                                float* __restrict__ out) {
  size_t i = (size_t)(blockIdx.x * 256 + threadIdx.x) * 8;
  float4 x0 = *(const float4*)(x + i);
  float4 x1 = *(const float4*)(x + i + 4);
  float s[8] = {x0.x, x0.y, x0.z, x0.w, x1.x, x1.y, x1.z, x1.w};
#pragma unroll
  for (int p = 0; p < 8; ++p) {
    u16x8 v = *(const u16x8*)(part + (size_t)p * (L_SEQ * DMODEL) + i);
#pragma unroll
    for (int j = 0; j < 8; ++j) s[j] += bf2f(v[j]);
  }
  float4 o0 = {s[0], s[1], s[2], s[3]};
  float4 o1 = {s[4], s[5], s[6], s[7]};
  *(float4*)(out + i) = o0;
  *(float4*)(out + i + 4) = o1;
}

// ---------------- q/k norm + RoPE + v copy (proj stride 3072) ----------------
__global__ __launch_bounds__(256) void qkv_prep(const u16* __restrict__ proj,
                                                const float* __restrict__ theta,
                                                const float* __restrict__ attn_scale,
                                                u16* __restrict__ qb, u16* __restrict__ kb,
                                                u16* __restrict__ vb) {
  const int l = blockIdx.x * 4 + (threadIdx.x >> 6);
  const int hd = blockIdx.y;
  const int e = threadIdx.x & 63;
  const u16* pr = proj + (size_t)l * (3 * DMODEL) + hd * EHEAD + e;
  float q = bf2f(pr[0]);
  float k = bf2f(pr[DMODEL]);
  float v = bf2f(pr[2 * DMODEL]);
  float sq = q * q, sk = k * k;
#pragma unroll
  for (int m = 1; m < 64; m <<= 1) {
    sq += __shfl_xor(sq, m);
    sk += __shfl_xor(sk, m);
  }
  float s = sqrtf(attn_scale[hd]);
  q *= LOG2E * s * rsqrtf(sq + 1e-6f);
  k *= s * rsqrtf(sk + 1e-6f);
  float ang = theta[((size_t)hd * L_SEQ + l) * 32 + (e & 31)];
  float cs = __cosf(ang), sn = __sinf(ang);
  float qp = __shfl_xor(q, 32), kp = __shfl_xor(k, 32);
  float qr = (e < 32) ? (q * cs - qp * sn) : (q * cs + qp * sn);
  float kr = (e < 32) ? (k * cs - kp * sn) : (k * cs + kp * sn);
  size_t o = ((size_t)hd * L_SEQ + l) * EHEAD + e;
  qb[o] = f2bf(qr);
  kb[o] = f2bf(kr);
  vb[o] = f2bf(v);
}

// ---------------- causal flash attention, split-KV x4, 32x32 MFMA ----------------
__global__ __launch_bounds__(128, 4) void attn_kernel(const u16* __restrict__ qb,
                                                      const u16* __restrict__ kb,
                                                      const u16* __restrict__ vb,
                                                      u16* __restrict__ po,
                                                      float* __restrict__ pm,
                                                      float* __restrict__ pl) {
  const int bid = blockIdx.x;
  const int s = 31 - (bid >> 6);
  const int hd = (bid >> 2) & 15;
  const int c = bid & 3;
  const int tid = threadIdx.x;
  const int lane = tid & 63;
  const int w = tid >> 6;
  const int h = lane >> 5;
  const int ql = lane & 31;
  const int qg = s * 64 + w * 32 + ql;
  const int nt = s + 1;
  const int t0 = (c * nt) >> 2;
  const int t1 = ((c + 1) * nt) >> 2;

  __shared__ u16 sK[64 * 64];
  __shared__ u16 sVT[64 * 64];

  const u16* Kh = kb + (size_t)hd * L_SEQ * EHEAD;
  const u16* Vh = vb + (size_t)hd * L_SEQ * EHEAD;
  const u16* Qh = qb + (size_t)hd * L_SEQ * EHEAD;

  bf16x8 qf[4];
#pragma unroll
  for (int es = 0; es < 4; ++es)
    qf[es] = *(const bf16x8*)(Qh + (size_t)qg * EHEAD + es * 16 + h * 8);

  f32x16 oa[2] = {};
  float m = NEGINF, lsum = 0.0f;

  const int vk = (tid & 15) * 4;
  const int ve = (tid >> 4) * 8;

  for (int kt = t0; kt < t1; ++kt) {
    const int k0 = kt * 64;
    __syncthreads();
#pragma unroll
    for (int i = 0; i < 4; ++i) {
      int r = w * 32 + i * 8 + (lane >> 3);
      const u16* src = Kh + (size_t)(k0 + r) * EHEAD + (((lane & 7) ^ (r & 7)) << 3);
      gld16(sK + (w * 32 + i * 8) * 64 + lane * 8, src);
    }
    u16x8 vr[4];
#pragma unroll
    for (int j = 0; j < 4; ++j)
      vr[j] = *(const u16x8*)(Vh + (size_t)(k0 + vk + j) * EHEAD + ve);
#pragma unroll
    for (int e = 0; e < 8; ++e) {
      int row = ve + e;
      int boff = row * 128 + ((((vk >> 3) ^ (row & 7)) << 4) | ((vk & 4) << 1));
      ushort4 pv;
      pv.x = vr[0][e]; pv.y = vr[1][e]; pv.z = vr[2][e]; pv.w = vr[3][e];
      *(ushort4*)((char*)sVT + boff) = pv;
    }
    __syncthreads();

    f32x16 st[2];
#pragma unroll
    for (int t = 0; t < 2; ++t) {
      f32x16 a = {};
      __builtin_amdgcn_s_setprio(1);
#pragma unroll
      for (int es = 0; es < 4; ++es) {
        int row = t * 32 + ql;
        int boff = row * 128 + (((es * 2 + h) ^ (row & 7)) << 4);
        bf16x8 kf = *(const bf16x8*)((const char*)sK + boff);
        a = __builtin_amdgcn_mfma_f32_32x32x16_bf16(kf, qf[es], a, 0, 0, 0);
      }
      __builtin_amdgcn_s_setprio(0);
      st[t] = a;
    }

    float p[2][16];
    float mx = NEGINF;
    const bool edge = (kt == s);
#pragma unroll
    for (int t = 0; t < 2; ++t)
#pragma unroll
      for (int r = 0; r < 16; ++r) {
        float v = st[t][r];
        if (edge) {
          int kg = k0 + t * 32 + (r & 3) + ((r >> 2) << 3) + h * 4;
          v = (kg > qg) ? NEGINF : v;
        }
        p[t][r] = v;
        mx = fmaxf(mx, v);
      }
    mx = fmaxf(mx, __shfl_xor(mx, 32));
    if (!__all(mx - m <= 8.0f)) {
      float mnew = fmaxf(m, mx);
      float alpha = EXP2F(m - mnew);
      lsum *= alpha;
#pragma unroll
      for (int et = 0; et < 2; ++et)
#pragma unroll
        for (int r = 0; r < 16; ++r) oa[et][r] *= alpha;
      m = mnew;
    }
    float ps = 0.0f;
#pragma unroll
    for (int t = 0; t < 2; ++t)
#pragma unroll
      for (int r = 0; r < 16; ++r) {
        float e_ = EXP2F(p[t][r] - m);
        p[t][r] = e_;
        ps += e_;
      }
    ps += __shfl_xor(ps, 32);
    lsum += ps;

    u32 pk_[2][8];
#pragma unroll
    for (int t = 0; t < 2; ++t)
#pragma unroll
      for (int i = 0; i < 8; ++i)
        asm("v_cvt_pk_bf16_f32 %0, %1, %2" : "=v"(pk_[t][i]) : "v"(p[t][2 * i]), "v"(p[t][2 * i + 1]));

#pragma unroll
    for (int ks = 0; ks < 4; ++ks) {
      const int tp = ks >> 1, base = (ks & 1) * 4;
      u32 s0 = h ? pk_[tp][base + 0] : pk_[tp][base + 2];
      u32 s1 = h ? pk_[tp][base + 1] : pk_[tp][base + 3];
      u32 r0 = (u32)__shfl_xor((int)s0, 32);
      u32 r1 = (u32)__shfl_xor((int)s1, 32);
      union { u32 u[4]; bf16x8 v; } pf;
      pf.u[0] = h ? r0 : pk_[tp][base + 0];
      pf.u[1] = h ? r1 : pk_[tp][base + 1];
      pf.u[2] = h ? pk_[tp][base + 2] : r0;
      pf.u[3] = h ? pk_[tp][base + 3] : r1;
      __builtin_amdgcn_s_setprio(1);
#pragma unroll
      for (int et = 0; et < 2; ++et) {
        int row = et * 32 + ql;
        int boff = row * 128 + (((ks * 2 + h) ^ (row & 7)) << 4);
        bf16x8 vf = *(const bf16x8*)((const char*)sVT + boff);
        oa[et] = __builtin_amdgcn_mfma_f32_32x32x16_bf16(vf, pf.v, oa[et], 0, 0, 0);
      }
      __builtin_amdgcn_s_setprio(0);
    }
  }

  const size_t pidx = (size_t)(s * 16 + hd) * 4 + c;
  u16* orow = po + pidx * 4096 + (size_t)(w * 32 + ql) * 64;
#pragma unroll
  for (int et = 0; et < 2; ++et)
#pragma unroll
    for (int g = 0; g < 4; ++g) {
      ushort4 ov;
      ov.x = f2bf(oa[et][4 * g + 0]);
      ov.y = f2bf(oa[et][4 * g + 1]);
      ov.z = f2bf(oa[et][4 * g + 2]);
      ov.w = f2bf(oa[et][4 * g + 3]);
      *(ushort4*)(orow + et * 32 + g * 8 + h * 4) = ov;
    }
  if (h == 0) {
    pm[pidx * 64 + w * 32 + ql] = m;
    pl[pidx * 64 + w * 32 + ql] = lsum;
  }
}

// ---------------- merge split-KV partials -> hb ----------------
__global__ __launch_bounds__(256) void attn_merge(const u16* __restrict__ po,
                                                  const float* __restrict__ pm,
                                                  const float* __restrict__ pl,
                                                  u16* __restrict__ hb) {
  const int sh = blockIdx.x;
  const int s = sh >> 4, hd = sh & 15;
  const int r = threadIdx.x >> 2;
  const int ec = (threadIdx.x & 3) << 4;
  float mc[4], wgt[4];
  float M = NEGINF;
#pragma unroll
  for (int c = 0; c < 4; ++c) {
    mc[c] = pm[(size_t)(sh * 4 + c) * 64 + r];
    M = fmaxf(M, mc[c]);
  }
  float L = 0.0f;
#pragma unroll
  for (int c = 0; c < 4; ++c) {
    wgt[c] = EXP2F(mc[c] - M);
    L += pl[(size_t)(sh * 4 + c) * 64 + r] * wgt[c];
  }
  float inv = 1.0f / L;
  float o[16] = {};
#pragma unroll
  for (int c = 0; c < 4; ++c) {
    const u16* pp = po + (size_t)(sh * 4 + c) * 4096 + r * 64 + ec;
    u16x8 v0 = *(const u16x8*)pp;
    u16x8 v1 = *(const u16x8*)(pp + 8);
#pragma unroll
    for (int j = 0; j < 8; ++j) {
      o[j] += wgt[c] * bf2f(v0[j]);
      o[8 + j] += wgt[c] * bf2f(v1[j]);
    }
  }
  u16* dst = hb + (size_t)(s * 64 + r) * FCAT + hd * EHEAD + ec;
  u16x8 out0, out1;
#pragma unroll
  for (int j = 0; j < 8; ++j) {
    out0[j] = f2bf(o[j] * inv);
    out1[j] = f2bf(o[8 + j] * inv);
  }
  *(u16x8*)dst = out0;
  *(u16x8*)(dst + 8) = out1;
}

extern "C" void kernel_launch(void* const* d_in, const int* in_sizes, int n_in,
                              void* d_out, int out_size, void* d_ws, size_t ws_size,
                              hipStream_t stream) {
  const float* x = (const float*)d_in[0];
  const float* theta = (const float*)d_in[1];
  const float* scale = (const float*)d_in[2];
  const float* w_in = (const float*)d_in[3];
  const float* w_out = (const float*)d_in[4];
  const float* attn_scale = (const float*)d_in[5];
  float* out = (float*)d_out;

  char* ws = (char*)d_ws;
  u16* w_out_b = (u16*)ws;   ws += (size_t)DMODEL * FCAT * 2;          // live: GEMM2 B
  u16* hb = (u16*)ws;        ws += (size_t)L_SEQ * FCAT * 2;           // live: GEMM2 A
  u16* xn = (u16*)ws;        ws += (size_t)L_SEQ * DMODEL * 2;         // dead after GEMM1
  u16* w_in_b = (u16*)ws;    ws += (size_t)FPROJ * DMODEL * 2;         // dead after GEMM1
  u16* proj = (u16*)ws;      ws += (size_t)L_SEQ * 3 * DMODEL * 2;     // dead after qkv_prep
  u16* qb = (u16*)ws;        ws += (size_t)NHEAD * L_SEQ * EHEAD * 2;  // dead after attn
  u16* kb = (u16*)ws;        ws += (size_t)NHEAD * L_SEQ * EHEAD * 2;
  u16* vb = (u16*)ws;        ws += (size_t)NHEAD * L_SEQ * EHEAD * 2;
  u16* po = xn;
  float* pm = (float*)(po + (size_t)512 * 4 * 4096);
  float* pl = pm + 512 * 4 * 64;
  u16* part = xn;

  const int na4 = FPROJ * DMODEL / 4, nb4 = DMODEL * FCAT / 4;
  const int ncvt = (na4 + nb4 + 255) / 256;
  prep_kernel<<<ncvt + L_SEQ, 256, 0, stream>>>(w_in, w_in_b, na4, w_out, w_out_b, nb4,
                                                ncvt, x, scale, xn);
  gemm256<1><<<(L_SEQ / 256) * (FPROJ / 256), 512, 0, stream>>>(xn, w_in_b, proj, hb,
                                                                L_SEQ, FPROJ, DMODEL);
  qkv_prep<<<dim3(L_SEQ / 4, NHEAD), 256, 0, stream>>>(proj, theta, attn_scale, qb, kb, vb);
  attn_kernel<<<2048, 128, 0, stream>>>(qb, kb, vb, po, pm, pl);
  attn_merge<<<512, 256, 0, stream>>>(po, pm, pl, hb);
  gemm256<2><<<dim3((L_SEQ / 256) * (DMODEL / 256), 8), 512, 0, stream>>>(hb, w_out_b, part,
                                                                          nullptr, L_SEQ, DMODEL, FCAT);
  combine8<<<L_SEQ * DMODEL / 8 / 256, 256, 0, stream>>>(part, x, out);
}

// Round 15
// 131.572 us; speedup vs baseline: 1.0607x; 1.0152x over previous
//
#include <hip/hip_runtime.h>

typedef unsigned short u16;
typedef unsigned int u32;
typedef __attribute__((ext_vector_type(8))) short bf16x8;
typedef __attribute__((ext_vector_type(8))) unsigned short u16x8;
typedef __attribute__((ext_vector_type(4))) float f32x4;
typedef __attribute__((ext_vector_type(16))) float f32x16;

#define L_SEQ 2048
#define DMODEL 1024
#define NHEAD 16
#define EHEAD 64
#define FPROJ 7168
#define FCAT 5120
#define NEGINF -1e30f
#define LOG2E 1.44269504088896f
#define EXP2F(x) __builtin_amdgcn_exp2f(x)

__device__ __forceinline__ u16 f2bf(float f) {
  union { float f; u32 u; } v; v.f = f;
  u32 r = v.u + 0x7FFFu + ((v.u >> 16) & 1u);
  return (u16)(r >> 16);
}
__device__ __forceinline__ float bf2f(u16 h) {
  union { u32 u; float f; } v; v.u = ((u32)h) << 16;
  return v.f;
}
__device__ __forceinline__ float gelu_f(float x) {
  float y = 0.7978845608028654f * (x + 0.044715f * x * x * x);
  float t = __expf(-2.0f * fabsf(y));
  float th = (1.0f - t) / (1.0f + t);
  th = (y < 0.0f) ? -th : th;
  return 0.5f * x * (1.0f + th);
}
__device__ __forceinline__ void gld16(void* lds, const void* g) {
  __builtin_amdgcn_global_load_lds((const __attribute__((address_space(1))) u32*)g,
                                   (__attribute__((address_space(3))) u32*)lds, 16, 0, 0);
}

// -------- prep: f32->bf16 weight convert (x2) + RMSNorm, one dispatch --------
__global__ __launch_bounds__(256) void prep_kernel(const float* __restrict__ a,
                                                   u16* __restrict__ oa, int na4,
                                                   const float* __restrict__ b,
                                                   u16* __restrict__ ob, int nb4,
                                                   int ncvt,
                                                   const float* __restrict__ x,
                                                   const float* __restrict__ scale,
                                                   u16* __restrict__ xn) {
  if ((int)blockIdx.x < ncvt) {
    int i = blockIdx.x * 256 + threadIdx.x;
    const float* src;
    u16* dst;
    int j;
    if (i < na4) { src = a; dst = oa; j = i; }
    else { j = i - na4; if (j >= nb4) return; src = b; dst = ob; }
    float4 v = ((const float4*)src)[j];
    ((u32*)dst)[2 * j] = (u32)f2bf(v.x) | ((u32)f2bf(v.y) << 16);
    ((u32*)dst)[2 * j + 1] = (u32)f2bf(v.z) | ((u32)f2bf(v.w) << 16);
    return;
  }
  int row = blockIdx.x - ncvt;
  const float4 v = ((const float4*)(x + (size_t)row * DMODEL))[threadIdx.x];
  float ss = v.x * v.x + v.y * v.y + v.z * v.z + v.w * v.w;
#pragma unroll
  for (int m = 1; m < 64; m <<= 1) ss += __shfl_xor(ss, m);
  __shared__ float ws[4];
  if ((threadIdx.x & 63) == 0) ws[threadIdx.x >> 6] = ss;
  __syncthreads();
  float tot = ws[0] + ws[1] + ws[2] + ws[3];
  float r = rsqrtf(tot * (1.0f / DMODEL) + 1e-6f);
  float4 sc = ((const float4*)scale)[threadIdx.x];
  u32 w0 = (u32)f2bf(v.x * r * (1.0f + sc.x)) | ((u32)f2bf(v.y * r * (1.0f + sc.y)) << 16);
  u32 w1 = (u32)f2bf(v.z * r * (1.0f + sc.z)) | ((u32)f2bf(v.w * r * (1.0f + sc.w)) << 16);
  u32* dst = (u32*)(xn + (size_t)row * DMODEL);
  dst[2 * threadIdx.x] = w0;
  dst[2 * threadIdx.x + 1] = w1;
}

// ---------------- 256x256 GEMM, 4 merged phases / 2 K-tiles, 1 barrier each ----------------
// Merged phase (BUF,HM): barrier; ds_read KH0; stage-early; 16 MFMA; ds_read KH1;
// stage-late; wait; 16 MFMA.  Stage slots (per 2-tile iter t,t+1):
//   Q1(b0,h0): B1h0 / B1h1    Q2(b0,h1): A1h1 / A0h0[t+2]
//   Q3(b1,h0): B0h0 / B0h1    Q4(b1,h1): A0h1 / A1h0[t+3]
// All stage->first-read distances >= 2 merged phases. End-of-phase waits:
// Q1 VMW6, Q2 VMW4, Q3 VMW6, Q4 VMW4 (edge-checked incl. prologue order).
__device__ __forceinline__ void stage_half(u16* lds, const u16* g, int K, int tid) {
#pragma unroll
  for (int i = 0; i < 2; ++i) {
    int idx = tid + i * 512;
    int r = idx >> 3;
    int gcb = ((idx & 7) << 4) ^ ((r & 7) << 4);
    gld16((char*)lds + idx * 16, (const char*)g + (size_t)r * K * 2 + gcb);
  }
}

#define GFENCE asm volatile("" ::: "memory")
#define VMW0 asm volatile("s_waitcnt vmcnt(0)" ::: "memory")
#define VMW4 asm volatile("s_waitcnt vmcnt(4)" ::: "memory")
#define VMW6 asm volatile("s_waitcnt vmcnt(6)" ::: "memory")
#define ST_A(BUF, T, HALF) stage_half(sA + (BUF) * 16384 + (HALF) * 8192, \
    Ab + (size_t)((HALF) * 128) * K + (T) * 64, K, tid)
#define ST_B(BUF, T, HALF) stage_half(sB + (BUF) * 16384 + (HALF) * 8192, \
    Bb + (size_t)((HALF) * 128) * K + (T) * 64, K, tid)

#define PHASE2(HM, BUFB, WCODE, STE, STL) do { \
    __builtin_amdgcn_s_barrier(); \
    const char* abA = (const char*)sA + (BUFB) * 32768 + (HM) * 16384 + frow * 128; \
    const char* bbB = (const char*)sB + (BUFB) * 32768 + (wn * 32 + frow) * 128; \
    bf16x8 af_[8], bv_[2]; \
    _Pragma("unroll") \
    for (int mr = 0; mr < 8; ++mr) af_[mr] = *(const bf16x8*)(abA + mr * 2048 + co0); \
    bv_[0] = *(const bf16x8*)(bbB + co0); \
    bv_[1] = *(const bf16x8*)(bbB + 2048 + co0); \
    GFENCE; \
    STE; \
    __builtin_amdgcn_s_setprio(1); \
    _Pragma("unroll") \
    for (int mr = 0; mr < 8; ++mr) { \
      acc[(HM) * 8 + mr][0] = __builtin_amdgcn_mfma_f32_16x16x32_bf16(af_[mr], bv_[0], acc[(HM) * 8 + mr][0], 0, 0, 0); \
      acc[(HM) * 8 + mr][1] = __builtin_amdgcn_mfma_f32_16x16x32_bf16(af_[mr], bv_[1], acc[(HM) * 8 + mr][1], 0, 0, 0); \
    } \
    __builtin_amdgcn_s_setprio(0); \
    _Pragma("unroll") \
    for (int mr = 0; mr < 8; ++mr) af_[mr] = *(const bf16x8*)(abA + mr * 2048 + co1); \
    bv_[0] = *(const bf16x8*)(bbB + co1); \
    bv_[1] = *(const bf16x8*)(bbB + 2048 + co1); \
    GFENCE; \
    STL; \
    WCODE; \
    __builtin_amdgcn_s_setprio(1); \
    _Pragma("unroll") \
    for (int mr = 0; mr < 8; ++mr) { \
      acc[(HM) * 8 + mr][0] = __builtin_amdgcn_mfma_f32_16x16x32_bf16(af_[mr], bv_[0], acc[(HM) * 8 + mr][0], 0, 0, 0); \
      acc[(HM) * 8 + mr][1] = __builtin_amdgcn_mfma_f32_16x16x32_bf16(af_[mr], bv_[1], acc[(HM) * 8 + mr][1], 0, 0, 0); \
    } \
    __builtin_amdgcn_s_setprio(0); \
  } while (0)

template <int OUTMODE>
__global__ __launch_bounds__(512, 2) void gemm256(const u16* __restrict__ A,
                                                  const u16* __restrict__ B,
                                                  u16* __restrict__ C0,
                                                  u16* __restrict__ C1,
                                                  int M, int N, int K) {
  __shared__ __align__(16) u16 smem[65536];
  u16* const sA = smem;
  u16* const sB = smem + 32768;
  const int tid = threadIdx.x;
  const int lane = tid & 63;
  const int wn = tid >> 6;
  const int frow = lane & 15;
  const int kbyte = ((lane >> 4) & 3) << 4;
  const int sw = (frow & 7) << 4;
  const int co0 = kbyte ^ sw;
  const int co1 = (64 | kbyte) ^ sw;

  const int nbx = N >> 8;
  const int nbm = (int)gridDim.x / nbx;
  const int v = (blockIdx.x & 7) * ((int)gridDim.x >> 3) + ((int)blockIdx.x >> 3);
  const int bm = v % nbm, bn = v / nbm;
  const int kper = K / (int)gridDim.y;
  const int kbeg = blockIdx.y * kper;
  const u16* Ab = A + (size_t)(bm * 256) * K + kbeg;
  const u16* Bb = B + (size_t)(bn * 256) * K + kbeg;

  f32x4 acc[16][2] = {};

  const int NT = kper >> 6;
  // prologue loads (per-thread order): A0h0(1-2), B0h0(3-4), B0h1(5-6), A0h1(7-8), A1h0(9-10)
  // Q1 needs first 6 -> VMW4 here + Q1's leading barrier.
  ST_A(0, 0, 0); ST_B(0, 0, 0); ST_B(0, 0, 1); ST_A(0, 0, 1); ST_A(1, 1, 0);
  VMW4;

  for (int kt = 0; kt < NT; kt += 2) {
    const int t1 = kt + 1;
    const int t2 = (kt + 2 >= NT) ? kt + 2 - NT : kt + 2;
    const int t3 = (kt + 3 >= NT) ? 0 : kt + 3;
    PHASE2(0, 0, VMW6, ST_B(1, t1, 0), ST_B(1, t1, 1));
    PHASE2(1, 0, VMW4, ST_A(1, t1, 1), ST_A(0, t2, 0));
    PHASE2(0, 1, VMW6, ST_B(0, t2, 0), ST_B(0, t2, 1));
    PHASE2(1, 1, VMW4, ST_A(0, t2, 1), ST_A(1, t3, 0));
  }

  // drain outstanding tail prefetch (it writes into smem, which we now reuse)
  VMW0;
  __syncthreads();

  const bool up = (OUTMODE == 1) && (bn >= 12);
  u16* const Cp2 = (OUTMODE == 2) ? C0 + (size_t)blockIdx.y * M * N : nullptr;

#pragma unroll
  for (int hm = 0; hm < 2; ++hm) {
#pragma unroll
    for (int m8 = 0; m8 < 8; ++m8) {
#pragma unroll
      for (int nr = 0; nr < 2; ++nr) {
        int col = wn * 32 + nr * 16 + frow;
#pragma unroll
        for (int r = 0; r < 4; ++r) {
          float vv = acc[hm * 8 + m8][nr][r];
          smem[(m8 * 16 + ((lane >> 4) * 4) + r) * 272 + col] = f2bf(up ? gelu_f(vv) : vv);
        }
      }
    }
    __syncthreads();
#pragma unroll
    for (int j = 0; j < 8; ++j) {
      int row = j * 16 + (tid >> 5);
      int c16 = (tid & 31) * 8;
      u16x8 vv = *(const u16x8*)&smem[row * 272 + c16];
      int gr = bm * 256 + hm * 128 + row;
      int gc = bn * 256 + c16;
      if (OUTMODE == 1) {
        if (!up) *(u16x8*)(C0 + (size_t)gr * (3 * DMODEL) + gc) = vv;
        else     *(u16x8*)(C1 + (size_t)gr * FCAT + (gc - 2048)) = vv;
      } else {
        *(u16x8*)(Cp2 + (size_t)gr * N + gc) = vv;
      }
    }
    __syncthreads();
  }
}

// ---------------- combine 8 bf16 split-K partials + skip -> f32 out ----------------
__global__ __launch_bounds__(256) void combine8(const u16* __restrict__ part,
                                                const float* __restrict__ x,
                                                float* __restrict__ out) {
  size_t i = (size_t)(blockIdx.x * 256 + threadIdx.x) * 8;
  float4 x0 = *(const float4*)(x + i);
  float4 x1 = *(const float4*)(x + i + 4);
  float s[8] = {x0.x, x0.y, x0.z, x0.w, x1.x, x1.y, x1.z, x1.w};
#pragma unroll
  for (int p = 0; p < 8; ++p) {
    u16x8 v = *(const u16x8*)(part + (size_t)p * (L_SEQ * DMODEL) + i);
#pragma unroll
    for (int j = 0; j < 8; ++j) s[j] += bf2f(v[j]);
  }
  float4 o0 = {s[0], s[1], s[2], s[3]};
  float4 o1 = {s[4], s[5], s[6], s[7]};
  *(float4*)(out + i) = o0;
  *(float4*)(out + i + 4) = o1;
}

// ---------------- q/k norm + RoPE + v copy (proj stride 3072) ----------------
__global__ __launch_bounds__(256) void qkv_prep(const u16* __restrict__ proj,
                                                const float* __restrict__ theta,
                                                const float* __restrict__ attn_scale,
                                                u16* __restrict__ qb, u16* __restrict__ kb,
                                                u16* __restrict__ vb) {
  const int l = blockIdx.x * 4 + (threadIdx.x >> 6);
  const int hd = blockIdx.y;
  const int e = threadIdx.x & 63;
  const u16* pr = proj + (size_t)l * (3 * DMODEL) + hd * EHEAD + e;
  float q = bf2f(pr[0]);
  float k = bf2f(pr[DMODEL]);
  float v = bf2f(pr[2 * DMODEL]);
  float sq = q * q, sk = k * k;
#pragma unroll
  for (int m = 1; m < 64; m <<= 1) {
    sq += __shfl_xor(sq, m);
    sk += __shfl_xor(sk, m);
  }
  float s = sqrtf(attn_scale[hd]);
  q *= LOG2E * s * rsqrtf(sq + 1e-6f);
  k *= s * rsqrtf(sk + 1e-6f);
  float ang = theta[((size_t)hd * L_SEQ + l) * 32 + (e & 31)];
  float cs = __cosf(ang), sn = __sinf(ang);
  float qp = __shfl_xor(q, 32), kp = __shfl_xor(k, 32);
  float qr = (e < 32) ? (q * cs - qp * sn) : (q * cs + qp * sn);
  float kr = (e < 32) ? (k * cs - kp * sn) : (k * cs + kp * sn);
  size_t o = ((size_t)hd * L_SEQ + l) * EHEAD + e;
  qb[o] = f2bf(qr);
  kb[o] = f2bf(kr);
  vb[o] = f2bf(v);
}

// ---------------- causal flash attention, split-KV x4, 32x32 MFMA ----------------
__global__ __launch_bounds__(128, 4) void attn_kernel(const u16* __restrict__ qb,
                                                      const u16* __restrict__ kb,
                                                      const u16* __restrict__ vb,
                                                      u16* __restrict__ po,
                                                      float* __restrict__ pm,
                                                      float* __restrict__ pl) {
  const int bid = blockIdx.x;
  const int s = 31 - (bid >> 6);
  const int hd = (bid >> 2) & 15;
  const int c = bid & 3;
  const int tid = threadIdx.x;
  const int lane = tid & 63;
  const int w = tid >> 6;
  const int h = lane >> 5;
  const int ql = lane & 31;
  const int qg = s * 64 + w * 32 + ql;
  const int nt = s + 1;
  const int t0 = (c * nt) >> 2;
  const int t1 = ((c + 1) * nt) >> 2;

  __shared__ u16 sK[64 * 64];
  __shared__ u16 sVT[64 * 64];

  const u16* Kh = kb + (size_t)hd * L_SEQ * EHEAD;
  const u16* Vh = vb + (size_t)hd * L_SEQ * EHEAD;
  const u16* Qh = qb + (size_t)hd * L_SEQ * EHEAD;

  bf16x8 qf[4];
#pragma unroll
  for (int es = 0; es < 4; ++es)
    qf[es] = *(const bf16x8*)(Qh + (size_t)qg * EHEAD + es * 16 + h * 8);

  f32x16 oa[2] = {};
  float m = NEGINF, lsum = 0.0f;

  const int vk = (tid & 15) * 4;
  const int ve = (tid >> 4) * 8;

  for (int kt = t0; kt < t1; ++kt) {
    const int k0 = kt * 64;
    __syncthreads();
#pragma unroll
    for (int i = 0; i < 4; ++i) {
      int r = w * 32 + i * 8 + (lane >> 3);
      const u16* src = Kh + (size_t)(k0 + r) * EHEAD + (((lane & 7) ^ (r & 7)) << 3);
      gld16(sK + (w * 32 + i * 8) * 64 + lane * 8, src);
    }
    u16x8 vr[4];
#pragma unroll
    for (int j = 0; j < 4; ++j)
      vr[j] = *(const u16x8*)(Vh + (size_t)(k0 + vk + j) * EHEAD + ve);
#pragma unroll
    for (int e = 0; e < 8; ++e) {
      int row = ve + e;
      int boff = row * 128 + ((((vk >> 3) ^ (row & 7)) << 4) | ((vk & 4) << 1));
      ushort4 pv;
      pv.x = vr[0][e]; pv.y = vr[1][e]; pv.z = vr[2][e]; pv.w = vr[3][e];
      *(ushort4*)((char*)sVT + boff) = pv;
    }
    __syncthreads();

    f32x16 st[2];
#pragma unroll
    for (int t = 0; t < 2; ++t) {
      f32x16 a = {};
      __builtin_amdgcn_s_setprio(1);
#pragma unroll
      for (int es = 0; es < 4; ++es) {
        int row = t * 32 + ql;
        int boff = row * 128 + (((es * 2 + h) ^ (row & 7)) << 4);
        bf16x8 kf = *(const bf16x8*)((const char*)sK + boff);
        a = __builtin_amdgcn_mfma_f32_32x32x16_bf16(kf, qf[es], a, 0, 0, 0);
      }
      __builtin_amdgcn_s_setprio(0);
      st[t] = a;
    }

    float p[2][16];
    float mx = NEGINF;
    const bool edge = (kt == s);
#pragma unroll
    for (int t = 0; t < 2; ++t)
#pragma unroll
      for (int r = 0; r < 16; ++r) {
        float v = st[t][r];
        if (edge) {
          int kg = k0 + t * 32 + (r & 3) + ((r >> 2) << 3) + h * 4;
          v = (kg > qg) ? NEGINF : v;
        }
        p[t][r] = v;
        mx = fmaxf(mx, v);
      }
    mx = fmaxf(mx, __shfl_xor(mx, 32));
    if (!__all(mx - m <= 8.0f)) {
      float mnew = fmaxf(m, mx);
      float alpha = EXP2F(m - mnew);
      lsum *= alpha;
#pragma unroll
      for (int et = 0; et < 2; ++et)
#pragma unroll
        for (int r = 0; r < 16; ++r) oa[et][r] *= alpha;
      m = mnew;
    }
    float ps = 0.0f;
#pragma unroll
    for (int t = 0; t < 2; ++t)
#pragma unroll
      for (int r = 0; r < 16; ++r) {
        float e_ = EXP2F(p[t][r] - m);
        p[t][r] = e_;
        ps += e_;
      }
    ps += __shfl_xor(ps, 32);
    lsum += ps;

    u32 pk_[2][8];
#pragma unroll
    for (int t = 0; t < 2; ++t)
#pragma unroll
      for (int i = 0; i < 8; ++i)
        asm("v_cvt_pk_bf16_f32 %0, %1, %2" : "=v"(pk_[t][i]) : "v"(p[t][2 * i]), "v"(p[t][2 * i + 1]));

#pragma unroll
    for (int ks = 0; ks < 4; ++ks) {
      const int tp = ks >> 1, base = (ks & 1) * 4;
      u32 s0 = h ? pk_[tp][base + 0] : pk_[tp][base + 2];
      u32 s1 = h ? pk_[tp][base + 1] : pk_[tp][base + 3];
      u32 r0 = (u32)__shfl_xor((int)s0, 32);
      u32 r1 = (u32)__shfl_xor((int)s1, 32);
      union { u32 u[4]; bf16x8 v; } pf;
      pf.u[0] = h ? r0 : pk_[tp][base + 0];
      pf.u[1] = h ? r1 : pk_[tp][base + 1];
      pf.u[2] = h ? pk_[tp][base + 2] : r0;
      pf.u[3] = h ? pk_[tp][base + 3] : r1;
      __builtin_amdgcn_s_setprio(1);
#pragma unroll
      for (int et = 0; et < 2; ++et) {
        int row = et * 32 + ql;
        int boff = row * 128 + (((ks * 2 + h) ^ (row & 7)) << 4);
        bf16x8 vf = *(const bf16x8*)((const char*)sVT + boff);
        oa[et] = __builtin_amdgcn_mfma_f32_32x32x16_bf16(vf, pf.v, oa[et], 0, 0, 0);
      }
      __builtin_amdgcn_s_setprio(0);
    }
  }

  const size_t pidx = (size_t)(s * 16 + hd) * 4 + c;
  u16* orow = po + pidx * 4096 + (size_t)(w * 32 + ql) * 64;
#pragma unroll
  for (int et = 0; et < 2; ++et)
#pragma unroll
    for (int g = 0; g < 4; ++g) {
      ushort4 ov;
      ov.x = f2bf(oa[et][4 * g + 0]);
      ov.y = f2bf(oa[et][4 * g + 1]);
      ov.z = f2bf(oa[et][4 * g + 2]);
      ov.w = f2bf(oa[et][4 * g + 3]);
      *(ushort4*)(orow + et * 32 + g * 8 + h * 4) = ov;
    }
  if (h == 0) {
    pm[pidx * 64 + w * 32 + ql] = m;
    pl[pidx * 64 + w * 32 + ql] = lsum;
  }
}

// ---------------- merge split-KV partials -> hb ----------------
__global__ __launch_bounds__(256) void attn_merge(const u16* __restrict__ po,
                                                  const float* __restrict__ pm,
                                                  const float* __restrict__ pl,
                                                  u16* __restrict__ hb) {
  const int sh = blockIdx.x;
  const int s = sh >> 4, hd = sh & 15;
  const int r = threadIdx.x >> 2;
  const int ec = (threadIdx.x & 3) << 4;
  float mc[4], wgt[4];
  float M = NEGINF;
#pragma unroll
  for (int c = 0; c < 4; ++c) {
    mc[c] = pm[(size_t)(sh * 4 + c) * 64 + r];
    M = fmaxf(M, mc[c]);
  }
  float L = 0.0f;
#pragma unroll
  for (int c = 0; c < 4; ++c) {
    wgt[c] = EXP2F(mc[c] - M);
    L += pl[(size_t)(sh * 4 + c) * 64 + r] * wgt[c];
  }
  float inv = 1.0f / L;
  float o[16] = {};
#pragma unroll
  for (int c = 0; c < 4; ++c) {
    const u16* pp = po + (size_t)(sh * 4 + c) * 4096 + r * 64 + ec;
    u16x8 v0 = *(const u16x8*)pp;
    u16x8 v1 = *(const u16x8*)(pp + 8);
#pragma unroll
    for (int j = 0; j < 8; ++j) {
      o[j] += wgt[c] * bf2f(v0[j]);
      o[8 + j] += wgt[c] * bf2f(v1[j]);
    }
  }
  u16* dst = hb + (size_t)(s * 64 + r) * FCAT + hd * EHEAD + ec;
  u16x8 out0, out1;
#pragma unroll
  for (int j = 0; j < 8; ++j) {
    out0[j] = f2bf(o[j] * inv);
    out1[j] = f2bf(o[8 + j] * inv);
  }
  *(u16x8*)dst = out0;
  *(u16x8*)(dst + 8) = out1;
}

extern "C" void kernel_launch(void* const* d_in, const int* in_sizes, int n_in,
                              void* d_out, int out_size, void* d_ws, size_t ws_size,
                              hipStream_t stream) {
  const float* x = (const float*)d_in[0];
  const float* theta = (const float*)d_in[1];
  const float* scale = (const float*)d_in[2];
  const float* w_in = (const float*)d_in[3];
  const float* w_out = (const float*)d_in[4];
  const float* attn_scale = (const float*)d_in[5];
  float* out = (float*)d_out;

  char* ws = (char*)d_ws;
  u16* w_out_b = (u16*)ws;   ws += (size_t)DMODEL * FCAT * 2;          // live: GEMM2 B
  u16* hb = (u16*)ws;        ws += (size_t)L_SEQ * FCAT * 2;           // live: GEMM2 A
  u16* xn = (u16*)ws;        ws += (size_t)L_SEQ * DMODEL * 2;         // dead after GEMM1
  u16* w_in_b = (u16*)ws;    ws += (size_t)FPROJ * DMODEL * 2;         // dead after GEMM1
  u16* proj = (u16*)ws;      ws += (size_t)L_SEQ * 3 * DMODEL * 2;     // dead after qkv_prep
  u16* qb = (u16*)ws;        ws += (size_t)NHEAD * L_SEQ * EHEAD * 2;  // dead after attn
  u16* kb = (u16*)ws;        ws += (size_t)NHEAD * L_SEQ * EHEAD * 2;
  u16* vb = (u16*)ws;        ws += (size_t)NHEAD * L_SEQ * EHEAD * 2;
  u16* po = xn;
  float* pm = (float*)(po + (size_t)512 * 4 * 4096);
  float* pl = pm + 512 * 4 * 64;
  u16* part = xn;

  const int na4 = FPROJ * DMODEL / 4, nb4 = DMODEL * FCAT / 4;
  const int ncvt = (na4 + nb4 + 255) / 256;
  prep_kernel<<<ncvt + L_SEQ, 256, 0, stream>>>(w_in, w_in_b, na4, w_out, w_out_b, nb4,
                                                ncvt, x, scale, xn);
  gemm256<1><<<(L_SEQ / 256) * (FPROJ / 256), 512, 0, stream>>>(xn, w_in_b, proj, hb,
                                                                L_SEQ, FPROJ, DMODEL);
  qkv_prep<<<dim3(L_SEQ / 4, NHEAD), 256, 0, stream>>>(proj, theta, attn_scale, qb, kb, vb);
  attn_kernel<<<2048, 128, 0, stream>>>(qb, kb, vb, po, pm, pl);
  attn_merge<<<512, 256, 0, stream>>>(po, pm, pl, hb);
  gemm256<2><<<dim3((L_SEQ / 256) * (DMODEL / 256), 8), 512, 0, stream>>>(hb, w_out_b, part,
                                                                          nullptr, L_SEQ, DMODEL, FCAT);
  combine8<<<L_SEQ * DMODEL / 8 / 256, 256, 0, stream>>>(part, x, out);
}